// Round 1
// baseline (6558.894 us; speedup 1.0000x reference)
//
#include <hip/hip_runtime.h>

#define NUSER 50000
#define NITEM 50000
#define NTOT  100000
#define DFEAT 4096
#define DLAT  128
#define DHID  512
#define MTILES 391           // ceil(50000/128)
#define MPAD  (MTILES*128)   // 50048

typedef __attribute__((ext_vector_type(8))) short bf16x8;
typedef __attribute__((ext_vector_type(4))) float f32x4;

__device__ __forceinline__ ushort f2bf(float f) {
  union { float f; unsigned u; } in; in.f = f;
  unsigned u = in.u;
  u += 0x7fffu + ((u >> 16) & 1u);   // round-to-nearest-even
  return (ushort)(u >> 16);
}

#define BM 128
#define BK 32
#define LDW 40   // padded LDS row stride (ushorts): keeps 16B alignment, breaks pow2 bank stride

// ---------------- GEMM1: hidden = leakyrelu(features @ W1 + b1), bf16 out ----------------
__global__ __launch_bounds__(256) void gemm1_kernel(
    const float* __restrict__ A,    // [NITEM][DFEAT] fp32
    const ushort* __restrict__ BT,  // [DHID][DFEAT] bf16 (W1 transposed)
    const float* __restrict__ bias, // [DHID]
    ushort* __restrict__ Hid)       // [MPAD][DHID] bf16
{
  __shared__ ushort As[BM][LDW];
  __shared__ ushort Bs[BM][LDW];
  const int tid = threadIdx.x;
  const int lane = tid & 63;
  const int wid = tid >> 6;
  const int wr = wid >> 1, wc = wid & 1;
  const int ntile = blockIdx.x & 3;       // N=512 -> 4 col tiles (fastest => L2 reuse of A)
  const int mtile = blockIdx.x >> 2;
  const int row0 = mtile * BM;
  const int col0 = ntile * BM;

  f32x4 acc[4][4];
  const f32x4 z = {0.f, 0.f, 0.f, 0.f};
  #pragma unroll
  for (int m = 0; m < 4; ++m)
    #pragma unroll
    for (int n = 0; n < 4; ++n) acc[m][n] = z;

  const int lrow = lane & 15;
  const int kb = (lane >> 4) * 8;

  for (int k0 = 0; k0 < DFEAT; k0 += BK) {
    // stage A (fp32 -> bf16): 128x32 = 1024 float4, 4 per thread
    #pragma unroll
    for (int j = 0; j < 4; ++j) {
      int idx = tid + j * 256;
      int r = idx >> 3;
      int c4 = (idx & 7) << 2;
      int grow = row0 + r;
      float4 v = make_float4(0.f, 0.f, 0.f, 0.f);
      if (grow < NITEM) v = *(const float4*)(A + (size_t)grow * DFEAT + k0 + c4);
      ushort4 b4; b4.x = f2bf(v.x); b4.y = f2bf(v.y); b4.z = f2bf(v.z); b4.w = f2bf(v.w);
      *(ushort4*)&As[r][c4] = b4;
    }
    // stage B (bf16 copy): 128x32 = 512 x (8 bf16), 2 per thread
    #pragma unroll
    for (int j = 0; j < 2; ++j) {
      int idx = tid + j * 256;
      int r = idx >> 2;
      int c8 = (idx & 3) << 3;
      *(uint4*)&Bs[r][c8] = *(const uint4*)(BT + (size_t)(col0 + r) * DFEAT + k0 + c8);
    }
    __syncthreads();
    bf16x8 a[4], b[4];
    #pragma unroll
    for (int m = 0; m < 4; ++m) a[m] = *(const bf16x8*)&As[wr * 64 + m * 16 + lrow][kb];
    #pragma unroll
    for (int n = 0; n < 4; ++n) b[n] = *(const bf16x8*)&Bs[wc * 64 + n * 16 + lrow][kb];
    #pragma unroll
    for (int m = 0; m < 4; ++m)
      #pragma unroll
      for (int n = 0; n < 4; ++n)
        acc[m][n] = __builtin_amdgcn_mfma_f32_16x16x32_bf16(a[m], b[n], acc[m][n], 0, 0, 0);
    __syncthreads();
  }
  // epilogue: +bias, leakyrelu(0.01), bf16 store (pad rows stored too; finite)
  #pragma unroll
  for (int n = 0; n < 4; ++n) {
    int col = col0 + wc * 64 + n * 16 + lrow;
    float bv = bias[col];
    #pragma unroll
    for (int m = 0; m < 4; ++m) {
      #pragma unroll
      for (int i = 0; i < 4; ++i) {
        int row = row0 + wr * 64 + m * 16 + (lane >> 4) * 4 + i;
        float v = acc[m][n][i] + bv;
        v = v > 0.f ? v : 0.01f * v;
        Hid[(size_t)row * DHID + col] = f2bf(v);
      }
    }
  }
}

// ---------------- GEMM2: item_feat = hidden @ W2 + b2 -> X rows [NUSER..NTOT) fp32 ----------------
__global__ __launch_bounds__(256) void gemm2_kernel(
    const ushort* __restrict__ A,   // Hid [MPAD][DHID] bf16
    const ushort* __restrict__ BT,  // W2T [DLAT][DHID] bf16
    const float* __restrict__ bias, // [DLAT]
    float* __restrict__ X)          // [NTOT][DLAT]
{
  __shared__ ushort As[BM][LDW];
  __shared__ ushort Bs[BM][LDW];
  const int tid = threadIdx.x;
  const int lane = tid & 63;
  const int wid = tid >> 6;
  const int wr = wid >> 1, wc = wid & 1;
  const int row0 = blockIdx.x * BM;

  f32x4 acc[4][4];
  const f32x4 z = {0.f, 0.f, 0.f, 0.f};
  #pragma unroll
  for (int m = 0; m < 4; ++m)
    #pragma unroll
    for (int n = 0; n < 4; ++n) acc[m][n] = z;

  const int lrow = lane & 15;
  const int kb = (lane >> 4) * 8;

  for (int k0 = 0; k0 < DHID; k0 += BK) {
    #pragma unroll
    for (int j = 0; j < 2; ++j) {
      int idx = tid + j * 256;
      int r = idx >> 2;
      int c8 = (idx & 3) << 3;
      *(uint4*)&As[r][c8] = *(const uint4*)(A + (size_t)(row0 + r) * DHID + k0 + c8);
      *(uint4*)&Bs[r][c8] = *(const uint4*)(BT + (size_t)r * DHID + k0 + c8);
    }
    __syncthreads();
    bf16x8 a[4], b[4];
    #pragma unroll
    for (int m = 0; m < 4; ++m) a[m] = *(const bf16x8*)&As[wr * 64 + m * 16 + lrow][kb];
    #pragma unroll
    for (int n = 0; n < 4; ++n) b[n] = *(const bf16x8*)&Bs[wc * 64 + n * 16 + lrow][kb];
    #pragma unroll
    for (int m = 0; m < 4; ++m)
      #pragma unroll
      for (int n = 0; n < 4; ++n)
        acc[m][n] = __builtin_amdgcn_mfma_f32_16x16x32_bf16(a[m], b[n], acc[m][n], 0, 0, 0);
    __syncthreads();
  }
  #pragma unroll
  for (int n = 0; n < 4; ++n) {
    int col = wc * 64 + n * 16 + lrow;    // < 128
    float bv = bias[col];
    #pragma unroll
    for (int m = 0; m < 4; ++m) {
      #pragma unroll
      for (int i = 0; i < 4; ++i) {
        int row = row0 + wr * 64 + m * 16 + (lane >> 4) * 4 + i;
        if (row < NITEM)
          X[(size_t)(NUSER + row) * DLAT + col] = acc[m][n][i] + bv;
      }
    }
  }
}

// ---------------- prep: transpose + fp32->bf16 for W1, W2 ----------------
__global__ void prep_w1t(const float* __restrict__ W1, ushort* __restrict__ W1T) {
  int idx = blockIdx.x * 256 + threadIdx.x;     // 512*4096 total
  int n = idx >> 12, k = idx & 4095;
  W1T[idx] = f2bf(W1[(size_t)k * DHID + n]);
}
__global__ void prep_w2t(const float* __restrict__ W2, ushort* __restrict__ W2T) {
  int idx = blockIdx.x * 256 + threadIdx.x;     // 128*512 total
  int n = idx >> 9, k = idx & 511;
  W2T[idx] = f2bf(W2[(size_t)k * DLAT + n]);
}

// ---------------- normalize rows of x (users from preference, items in-place) ----------------
__global__ __launch_bounds__(256) void normalize_kernel(
    const float* __restrict__ pref, float* __restrict__ X) {
  int gw = (blockIdx.x * 256 + threadIdx.x) >> 6;   // one wave per row
  int lane = threadIdx.x & 63;
  if (gw >= NTOT) return;
  const float* src = (gw < NUSER) ? (pref + (size_t)gw * DLAT) : (X + (size_t)gw * DLAT);
  float2 v = *(const float2*)(src + lane * 2);
  float s = v.x * v.x + v.y * v.y;
  #pragma unroll
  for (int off = 32; off; off >>= 1) s += __shfl_xor(s, off, 64);
  float inv = 1.0f / fmaxf(sqrtf(s), 1e-12f);
  float2 o; o.x = v.x * inv; o.y = v.y * inv;
  *(float2*)(X + (size_t)gw * DLAT + lane * 2) = o;
}

// ---------------- graph prep ----------------
__global__ void deg_kernel(const int* __restrict__ row, float* __restrict__ deg, int E) {
  int e = blockIdx.x * 256 + threadIdx.x;
  if (e < E) atomicAdd(&deg[row[e]], 1.0f);
}
__global__ void rsqrt_kernel(float* __restrict__ deg, int n) {
  int i = blockIdx.x * 256 + threadIdx.x;
  if (i < n) deg[i] = rsqrtf(deg[i]);   // deg==0 -> inf, never used on edges
}
__global__ void edgenorm_kernel(const int* __restrict__ row, const int* __restrict__ col,
                                const float* __restrict__ dis, float* __restrict__ enorm, int E) {
  int e = blockIdx.x * 256 + threadIdx.x;
  if (e < E) enorm[e] = dis[row[e]] * dis[col[e]];
}

// ---------------- scatter: hout[col] += norm * h[row], edge-parallel ----------------
__global__ __launch_bounds__(256) void scatter_kernel(
    const int* __restrict__ row, const int* __restrict__ col,
    const float* __restrict__ enorm, const float* __restrict__ h,
    float* __restrict__ hout, int E) {
  long long t = (long long)blockIdx.x * 256 + threadIdx.x;
  int e = (int)(t >> 5);
  int c = ((int)t & 31) * 4;
  if (e >= E) return;
  int r = row[e], d = col[e];
  float w = enorm[e];
  float4 v = *(const float4*)(h + (size_t)r * DLAT + c);
  float* o = hout + (size_t)d * DLAT + c;
  atomicAdd(o + 0, w * v.x);
  atomicAdd(o + 1, w * v.y);
  atomicAdd(o + 2, w * v.z);
  atomicAdd(o + 3, w * v.w);
}

// ---------------- final combine: out = x + h1 + h2 ----------------
__global__ void combine_kernel(const float* __restrict__ x, const float* __restrict__ hA,
                               const float* __restrict__ hB, float* __restrict__ out, int n4) {
  int i = blockIdx.x * 256 + threadIdx.x;
  if (i >= n4) return;
  float4 a = ((const float4*)x)[i];
  float4 b = ((const float4*)hA)[i];
  float4 c = ((const float4*)hB)[i];
  float4 o; o.x = a.x + b.x + c.x; o.y = a.y + b.y + c.y;
  o.z = a.z + b.z + c.z; o.w = a.w + b.w + c.w;
  ((float4*)out)[i] = o;
}

extern "C" void kernel_launch(void* const* d_in, const int* in_sizes, int n_in,
                              void* d_out, int out_size, void* d_ws, size_t ws_size,
                              hipStream_t stream) {
  const float* features  = (const float*)d_in[0];
  const float* preference = (const float*)d_in[1];
  const float* W1 = (const float*)d_in[2];
  const float* b1 = (const float*)d_in[3];
  const float* W2 = (const float*)d_in[4];
  const float* b2 = (const float*)d_in[5];
  const int*   edges = (const int*)d_in[6];
  const int E = in_sizes[6] / 2;
  const int* erow = edges;
  const int* ecol = edges + E;
  float* out = (float*)d_out;

  char* ws = (char*)d_ws;
  size_t off = 0;
  auto alloc = [&](size_t bytes) {
    void* p = ws + off;
    off = (off + bytes + 255) & ~(size_t)255;
    return p;
  };
  ushort* W1T  = (ushort*)alloc((size_t)DHID * DFEAT * 2);   // 4.2 MB
  ushort* W2T  = (ushort*)alloc((size_t)DLAT * DHID * 2);    // 0.13 MB
  ushort* Hid  = (ushort*)alloc((size_t)MPAD * DHID * 2);    // 51.2 MB
  float*  X    = (float*)alloc((size_t)NTOT * DLAT * 4);     // 51.2 MB
  float*  hA   = (float*)alloc((size_t)NTOT * DLAT * 4);     // 51.2 MB
  float*  hB   = (float*)alloc((size_t)NTOT * DLAT * 4);     // 51.2 MB
  float*  deg  = (float*)alloc((size_t)NTOT * 4);            // 0.4 MB
  float*  enorm = (float*)alloc((size_t)E * 4);              // 6.4 MB

  prep_w1t<<<(DHID * DFEAT) / 256, 256, 0, stream>>>(W1, W1T);
  prep_w2t<<<(DLAT * DHID) / 256, 256, 0, stream>>>(W2, W2T);
  gemm1_kernel<<<MTILES * 4, 256, 0, stream>>>(features, W1T, b1, Hid);
  gemm2_kernel<<<MTILES, 256, 0, stream>>>(Hid, W2T, b2, X);
  normalize_kernel<<<(NTOT * 64 + 255) / 256, 256, 0, stream>>>(preference, X);

  hipMemsetAsync(deg, 0, (size_t)NTOT * 4, stream);
  deg_kernel<<<(E + 255) / 256, 256, 0, stream>>>(erow, deg, E);
  rsqrt_kernel<<<(NTOT + 255) / 256, 256, 0, stream>>>(deg, NTOT);
  edgenorm_kernel<<<(E + 255) / 256, 256, 0, stream>>>(erow, ecol, deg, enorm, E);

  hipMemsetAsync(hA, 0, (size_t)NTOT * DLAT * 4, stream);
  scatter_kernel<<<(int)(((long long)E * 32 + 255) / 256), 256, 0, stream>>>(erow, ecol, enorm, X, hA, E);
  hipMemsetAsync(hB, 0, (size_t)NTOT * DLAT * 4, stream);
  scatter_kernel<<<(int)(((long long)E * 32 + 255) / 256), 256, 0, stream>>>(erow, ecol, enorm, hA, hB, E);

  combine_kernel<<<(NTOT * DLAT / 4 + 255) / 256, 256, 0, stream>>>(X, hA, hB, out, NTOT * DLAT / 4);
  hipMemcpyAsync(out + (size_t)NTOT * DLAT, preference, (size_t)NUSER * DLAT * 4,
                 hipMemcpyDeviceToDevice, stream);
}

// Round 2
// 1557.581 us; speedup vs baseline: 4.2109x; 4.2109x over previous
//
#include <hip/hip_runtime.h>

#define NUSER 50000
#define NITEM 50000
#define NTOT  100000
#define DFEAT 4096
#define DLAT  128
#define DHID  512
#define MTILES 391           // ceil(50000/128)
#define MPAD  (MTILES*128)   // 50048

typedef __attribute__((ext_vector_type(8))) short bf16x8;
typedef __attribute__((ext_vector_type(4))) float f32x4;

__device__ __forceinline__ ushort f2bf(float f) {
  union { float f; unsigned u; } in; in.f = f;
  unsigned u = in.u;
  u += 0x7fffu + ((u >> 16) & 1u);   // round-to-nearest-even
  return (ushort)(u >> 16);
}

#define BM 128
#define BK 32
#define LDW 40   // padded LDS row stride (ushorts)

// ---------------- GEMM1: hidden = leakyrelu(features @ W1 + b1), bf16 out ----------------
__global__ __launch_bounds__(256) void gemm1_kernel(
    const float* __restrict__ A,    // [NITEM][DFEAT] fp32
    const ushort* __restrict__ BT,  // [DHID][DFEAT] bf16 (W1 transposed)
    const float* __restrict__ bias, // [DHID]
    ushort* __restrict__ Hid)       // [MPAD][DHID] bf16
{
  __shared__ ushort As[BM][LDW];
  __shared__ ushort Bs[BM][LDW];
  const int tid = threadIdx.x;
  const int lane = tid & 63;
  const int wid = tid >> 6;
  const int wr = wid >> 1, wc = wid & 1;
  const int ntile = blockIdx.x & 3;
  const int mtile = blockIdx.x >> 2;
  const int row0 = mtile * BM;
  const int col0 = ntile * BM;

  f32x4 acc[4][4];
  const f32x4 z = {0.f, 0.f, 0.f, 0.f};
  #pragma unroll
  for (int m = 0; m < 4; ++m)
    #pragma unroll
    for (int n = 0; n < 4; ++n) acc[m][n] = z;

  const int lrow = lane & 15;
  const int kb = (lane >> 4) * 8;

  for (int k0 = 0; k0 < DFEAT; k0 += BK) {
    #pragma unroll
    for (int j = 0; j < 4; ++j) {
      int idx = tid + j * 256;
      int r = idx >> 3;
      int c4 = (idx & 7) << 2;
      int grow = row0 + r;
      float4 v = make_float4(0.f, 0.f, 0.f, 0.f);
      if (grow < NITEM) v = *(const float4*)(A + (size_t)grow * DFEAT + k0 + c4);
      ushort4 b4; b4.x = f2bf(v.x); b4.y = f2bf(v.y); b4.z = f2bf(v.z); b4.w = f2bf(v.w);
      *(ushort4*)&As[r][c4] = b4;
    }
    #pragma unroll
    for (int j = 0; j < 2; ++j) {
      int idx = tid + j * 256;
      int r = idx >> 2;
      int c8 = (idx & 3) << 3;
      *(uint4*)&Bs[r][c8] = *(const uint4*)(BT + (size_t)(col0 + r) * DFEAT + k0 + c8);
    }
    __syncthreads();
    bf16x8 a[4], b[4];
    #pragma unroll
    for (int m = 0; m < 4; ++m) a[m] = *(const bf16x8*)&As[wr * 64 + m * 16 + lrow][kb];
    #pragma unroll
    for (int n = 0; n < 4; ++n) b[n] = *(const bf16x8*)&Bs[wc * 64 + n * 16 + lrow][kb];
    #pragma unroll
    for (int m = 0; m < 4; ++m)
      #pragma unroll
      for (int n = 0; n < 4; ++n)
        acc[m][n] = __builtin_amdgcn_mfma_f32_16x16x32_bf16(a[m], b[n], acc[m][n], 0, 0, 0);
    __syncthreads();
  }
  #pragma unroll
  for (int n = 0; n < 4; ++n) {
    int col = col0 + wc * 64 + n * 16 + lrow;
    float bv = bias[col];
    #pragma unroll
    for (int m = 0; m < 4; ++m) {
      #pragma unroll
      for (int i = 0; i < 4; ++i) {
        int row = row0 + wr * 64 + m * 16 + (lane >> 4) * 4 + i;
        float v = acc[m][n][i] + bv;
        v = v > 0.f ? v : 0.01f * v;
        Hid[(size_t)row * DHID + col] = f2bf(v);
      }
    }
  }
}

// ---------------- GEMM2: item_feat = hidden @ W2 + b2 -> X rows [NUSER..NTOT) fp32 ----------------
__global__ __launch_bounds__(256) void gemm2_kernel(
    const ushort* __restrict__ A,   // Hid [MPAD][DHID] bf16
    const ushort* __restrict__ BT,  // W2T [DLAT][DHID] bf16
    const float* __restrict__ bias, // [DLAT]
    float* __restrict__ X)          // [NTOT][DLAT]
{
  __shared__ ushort As[BM][LDW];
  __shared__ ushort Bs[BM][LDW];
  const int tid = threadIdx.x;
  const int lane = tid & 63;
  const int wid = tid >> 6;
  const int wr = wid >> 1, wc = wid & 1;
  const int row0 = blockIdx.x * BM;

  f32x4 acc[4][4];
  const f32x4 z = {0.f, 0.f, 0.f, 0.f};
  #pragma unroll
  for (int m = 0; m < 4; ++m)
    #pragma unroll
    for (int n = 0; n < 4; ++n) acc[m][n] = z;

  const int lrow = lane & 15;
  const int kb = (lane >> 4) * 8;

  for (int k0 = 0; k0 < DHID; k0 += BK) {
    #pragma unroll
    for (int j = 0; j < 2; ++j) {
      int idx = tid + j * 256;
      int r = idx >> 2;
      int c8 = (idx & 3) << 3;
      *(uint4*)&As[r][c8] = *(const uint4*)(A + (size_t)(row0 + r) * DHID + k0 + c8);
      *(uint4*)&Bs[r][c8] = *(const uint4*)(BT + (size_t)r * DHID + k0 + c8);
    }
    __syncthreads();
    bf16x8 a[4], b[4];
    #pragma unroll
    for (int m = 0; m < 4; ++m) a[m] = *(const bf16x8*)&As[wr * 64 + m * 16 + lrow][kb];
    #pragma unroll
    for (int n = 0; n < 4; ++n) b[n] = *(const bf16x8*)&Bs[wc * 64 + n * 16 + lrow][kb];
    #pragma unroll
    for (int m = 0; m < 4; ++m)
      #pragma unroll
      for (int n = 0; n < 4; ++n)
        acc[m][n] = __builtin_amdgcn_mfma_f32_16x16x32_bf16(a[m], b[n], acc[m][n], 0, 0, 0);
    __syncthreads();
  }
  #pragma unroll
  for (int n = 0; n < 4; ++n) {
    int col = wc * 64 + n * 16 + lrow;
    float bv = bias[col];
    #pragma unroll
    for (int m = 0; m < 4; ++m) {
      #pragma unroll
      for (int i = 0; i < 4; ++i) {
        int row = row0 + wr * 64 + m * 16 + (lane >> 4) * 4 + i;
        if (row < NITEM)
          X[(size_t)(NUSER + row) * DLAT + col] = acc[m][n][i] + bv;
      }
    }
  }
}

// ---------------- prep: transpose + fp32->bf16 for W1, W2 ----------------
__global__ void prep_w1t(const float* __restrict__ W1, ushort* __restrict__ W1T) {
  int idx = blockIdx.x * 256 + threadIdx.x;
  int n = idx >> 12, k = idx & 4095;
  W1T[idx] = f2bf(W1[(size_t)k * DHID + n]);
}
__global__ void prep_w2t(const float* __restrict__ W2, ushort* __restrict__ W2T) {
  int idx = blockIdx.x * 256 + threadIdx.x;
  int n = idx >> 9, k = idx & 511;
  W2T[idx] = f2bf(W2[(size_t)k * DLAT + n]);
}

// ---------------- normalize rows of x (users from preference, items in-place) ----------------
__global__ __launch_bounds__(256) void normalize_kernel(
    const float* __restrict__ pref, float* __restrict__ X) {
  int gw = (blockIdx.x * 256 + threadIdx.x) >> 6;
  int lane = threadIdx.x & 63;
  if (gw >= NTOT) return;
  const float* src = (gw < NUSER) ? (pref + (size_t)gw * DLAT) : (X + (size_t)gw * DLAT);
  float2 v = *(const float2*)(src + lane * 2);
  float s = v.x * v.x + v.y * v.y;
  #pragma unroll
  for (int off = 32; off; off >>= 1) s += __shfl_xor(s, off, 64);
  float inv = 1.0f / fmaxf(sqrtf(s), 1e-12f);
  float2 o; o.x = v.x * inv; o.y = v.y * inv;
  *(float2*)(X + (size_t)gw * DLAT + lane * 2) = o;
}

// ---------------- graph prep: CSR by destination ----------------
// NOTE: edge list is symmetric (u->i and i->u both present), so per-node
// source-count == dest-count: one counting pass gives deg AND CSR sizes.
__global__ void count_kernel(const int* __restrict__ col, int* __restrict__ cnt, int E) {
  int e = blockIdx.x * 256 + threadIdx.x;
  if (e < E) atomicAdd(&cnt[col[e]], 1);
}
__global__ void dinv_kernel(const int* __restrict__ cnt, float* __restrict__ dinv, int n) {
  int i = blockIdx.x * 256 + threadIdx.x;
  if (i < n) dinv[i] = rsqrtf((float)cnt[i]);   // inf for deg 0, never used on edges
}

// single-block chunked exclusive scan over n counts -> off[0..n]
__global__ __launch_bounds__(1024) void scan_kernel(const int* __restrict__ cnt,
                                                    int* __restrict__ off, int n) {
  __shared__ int ws[16];
  __shared__ int wexcl[16];
  __shared__ int total_s;
  __shared__ int carry_s;
  const int tid = threadIdx.x, lane = tid & 63, wv = tid >> 6;
  if (tid == 0) carry_s = 0;
  __syncthreads();
  for (int base = 0; base < n; base += 1024) {
    int i = base + tid;
    int v = (i < n) ? cnt[i] : 0;
    int x = v;
    #pragma unroll
    for (int o = 1; o < 64; o <<= 1) {
      int t = __shfl_up(x, o, 64);
      if (lane >= o) x += t;
    }
    if (lane == 63) ws[wv] = x;
    __syncthreads();
    if (tid < 16) {
      int y = ws[tid];
      #pragma unroll
      for (int o = 1; o < 16; o <<= 1) {
        int t = __shfl_up(y, o, 64);
        if (tid >= o) y += t;
      }
      wexcl[tid] = y - ws[tid];
      if (tid == 15) total_s = y;
    }
    __syncthreads();
    int carry = carry_s;
    if (i < n) off[i] = carry + wexcl[wv] + (x - v);
    __syncthreads();
    if (tid == 0) carry_s = carry + total_s;
    __syncthreads();
  }
  if (threadIdx.x == 0) off[n] = carry_s;
}

// fill CSR slots: (src, edge-norm) packed per dst segment
__global__ void fill_kernel(const int* __restrict__ row, const int* __restrict__ col,
                            const float* __restrict__ dinv, const int* __restrict__ off,
                            int* __restrict__ cur, int2* __restrict__ srcw, int E) {
  int e = blockIdx.x * 256 + threadIdx.x;
  if (e >= E) return;
  int r = row[e], c = col[e];
  float w = dinv[r] * dinv[c];
  int p = atomicAdd(&cur[c], 1);
  int2 pk; pk.x = r; pk.y = __float_as_int(w);
  srcw[off[c] + p] = pk;
}

// ---------------- SpMM: one wave per node, register accumulate, no atomics ----------------
template <int FINAL>
__global__ __launch_bounds__(256) void spmm_kernel(
    const int2* __restrict__ srcw, const int* __restrict__ off,
    const float* __restrict__ h, float* __restrict__ hout,
    const float* __restrict__ addA, const float* __restrict__ addB) {
  int node = (int)((blockIdx.x * 256 + threadIdx.x) >> 6);
  int lane = threadIdx.x & 63;
  if (node >= NTOT) return;
  int p = off[node], pend = off[node + 1];
  float ax = 0.f, ay = 0.f;
  // unroll by 2 for gather ILP
  for (; p + 1 < pend; p += 2) {
    int2 e0 = srcw[p];
    int2 e1 = srcw[p + 1];
    float w0 = __int_as_float(e0.y);
    float w1 = __int_as_float(e1.y);
    float2 v0 = *(const float2*)(h + (size_t)e0.x * DLAT + lane * 2);
    float2 v1 = *(const float2*)(h + (size_t)e1.x * DLAT + lane * 2);
    ax += w0 * v0.x + w1 * v1.x;
    ay += w0 * v0.y + w1 * v1.y;
  }
  if (p < pend) {
    int2 e0 = srcw[p];
    float w0 = __int_as_float(e0.y);
    float2 v0 = *(const float2*)(h + (size_t)e0.x * DLAT + lane * 2);
    ax += w0 * v0.x;
    ay += w0 * v0.y;
  }
  size_t o = (size_t)node * DLAT + lane * 2;
  if (FINAL) {
    float2 a = *(const float2*)(addA + o);
    float2 b = *(const float2*)(addB + o);
    ax += a.x + b.x;
    ay += a.y + b.y;
  }
  float2 r; r.x = ax; r.y = ay;
  *(float2*)(hout + o) = r;
}

extern "C" void kernel_launch(void* const* d_in, const int* in_sizes, int n_in,
                              void* d_out, int out_size, void* d_ws, size_t ws_size,
                              hipStream_t stream) {
  const float* features  = (const float*)d_in[0];
  const float* preference = (const float*)d_in[1];
  const float* W1 = (const float*)d_in[2];
  const float* b1 = (const float*)d_in[3];
  const float* W2 = (const float*)d_in[4];
  const float* b2 = (const float*)d_in[5];
  const int*   edges = (const int*)d_in[6];
  const int E = in_sizes[6] / 2;
  const int* erow = edges;
  const int* ecol = edges + E;
  float* out = (float*)d_out;

  char* ws = (char*)d_ws;
  size_t off_b = 0;
  auto alloc = [&](size_t bytes) {
    void* p = ws + off_b;
    off_b = (off_b + bytes + 255) & ~(size_t)255;
    return p;
  };
  ushort* W1T  = (ushort*)alloc((size_t)DHID * DFEAT * 2);   // 4.2 MB
  ushort* W2T  = (ushort*)alloc((size_t)DLAT * DHID * 2);    // 0.13 MB
  ushort* Hid  = (ushort*)alloc((size_t)MPAD * DHID * 2);    // 51.2 MB
  float*  X    = (float*)alloc((size_t)NTOT * DLAT * 4);     // 51.2 MB
  float*  hA   = (float*)alloc((size_t)NTOT * DLAT * 4);     // 51.2 MB
  int*    cnt  = (int*)alloc((size_t)NTOT * 4);
  int*    offs = (int*)alloc((size_t)(NTOT + 1) * 4);
  int*    cur  = (int*)alloc((size_t)NTOT * 4);
  float*  dinv = (float*)alloc((size_t)NTOT * 4);
  int2*   srcw = (int2*)alloc((size_t)E * 8);                // 12.8 MB

  // projection MLP + normalize
  prep_w1t<<<(DHID * DFEAT) / 256, 256, 0, stream>>>(W1, W1T);
  prep_w2t<<<(DLAT * DHID) / 256, 256, 0, stream>>>(W2, W2T);
  gemm1_kernel<<<MTILES * 4, 256, 0, stream>>>(features, W1T, b1, Hid);
  gemm2_kernel<<<MTILES, 256, 0, stream>>>(Hid, W2T, b2, X);
  normalize_kernel<<<(NTOT * 64 + 255) / 256, 256, 0, stream>>>(preference, X);

  // CSR build (by destination); symmetric edge list => cnt doubles as deg
  hipMemsetAsync(cnt, 0, (size_t)NTOT * 4, stream);
  count_kernel<<<(E + 255) / 256, 256, 0, stream>>>(ecol, cnt, E);
  dinv_kernel<<<(NTOT + 255) / 256, 256, 0, stream>>>(cnt, dinv, NTOT);
  scan_kernel<<<1, 1024, 0, stream>>>(cnt, offs, NTOT);
  hipMemsetAsync(cur, 0, (size_t)NTOT * 4, stream);
  fill_kernel<<<(E + 255) / 256, 256, 0, stream>>>(erow, ecol, dinv, offs, cur, srcw, E);

  // two propagation layers; layer 2 fuses out = X + h1 + h2
  spmm_kernel<0><<<(NTOT * 64 + 255) / 256, 256, 0, stream>>>(srcw, offs, X, hA, nullptr, nullptr);
  spmm_kernel<1><<<(NTOT * 64 + 255) / 256, 256, 0, stream>>>(srcw, offs, hA, out, X, hA);

  // output 1: preference passthrough
  hipMemcpyAsync(out + (size_t)NTOT * DLAT, preference, (size_t)NUSER * DLAT * 4,
                 hipMemcpyDeviceToDevice, stream);
}

// Round 3
// 963.685 us; speedup vs baseline: 6.8061x; 1.6163x over previous
//
#include <hip/hip_runtime.h>

#define NUSER 50000
#define NITEM 50000
#define NTOT  100000
#define DFEAT 4096
#define DLAT  128
#define DHID  512
#define MTILES 391           // ceil(50000/128)
#define MPAD  (MTILES*128)   // 50048

typedef __attribute__((ext_vector_type(8))) short bf16x8;
typedef __attribute__((ext_vector_type(4))) float f32x4;

__device__ __forceinline__ ushort f2bf(float f) {
  union { float f; unsigned u; } in; in.f = f;
  unsigned u = in.u;
  u += 0x7fffu + ((u >> 16) & 1u);   // round-to-nearest-even
  return (ushort)(u >> 16);
}
__device__ __forceinline__ unsigned pk2bf(float lo, float hi) {
  return (unsigned)f2bf(lo) | ((unsigned)f2bf(hi) << 16);
}

// ================= GEMM1: Hid = leakyrelu(A(fp32) @ W1 + b1) =================
// BM=128, BN=512(=DHID, so A is read exactly once), BK=64.
// 8 waves (512 thr); wave tile 64x128 -> acc 4x8 fragments.
// LDS (dynamic, 80KB): As[128][64] bf16 swizzled, Bs[512][64] bf16 swizzled.
// Swizzle: 16B slot s of row r holds k-group (s ^ (r&7)) -> conflict-free
// ds_write + ds_read in 8-lane groups. B staged via global_load_lds with
// pre-swizzled global source (linear LDS dest = lane*16).
__global__ __launch_bounds__(512) void gemm1_kernel(
    const float* __restrict__ A,    // [NITEM][DFEAT] fp32
    const ushort* __restrict__ BT,  // [DHID][DFEAT] bf16 (W1 transposed)
    const float* __restrict__ bias, // [DHID]
    ushort* __restrict__ Hid)       // [MPAD][DHID] bf16
{
  extern __shared__ char smem[];
  char* AsB = smem;            // 128*64*2 = 16384 B
  char* BsB = smem + 16384;    // 512*64*2 = 65536 B

  const int tid = threadIdx.x;
  const int lane = tid & 63;
  const int wid = tid >> 6;          // 0..7
  const int wr = wid >> 2;           // 0..1  (row half)
  const int wc = wid & 3;            // 0..3  (col quarter)
  const int row0 = blockIdx.x * 128;

  const int lr = lane & 15;
  const int l7 = lane & 7;
  const int kq = lane >> 4;          // 0..3

  f32x4 acc[4][8];
  const f32x4 z = {0.f, 0.f, 0.f, 0.f};
  #pragma unroll
  for (int m = 0; m < 4; ++m)
    #pragma unroll
    for (int n = 0; n < 8; ++n) acc[m][n] = z;

  // A-stage constants: thread handles slots q=tid and q+512 (q = r*8+t)
  const int ar0 = tid >> 3, at0 = tid & 7;
  const int ar1 = (tid + 512) >> 3, at1 = tid & 7;   // t repeats every 8
  const size_t asrc0 = (size_t)(row0 + ar0) * DFEAT + at0 * 8;
  const size_t asrc1 = (size_t)(row0 + ar1) * DFEAT + at1 * 8;
  char* adst0 = AsB + ar0 * 128 + ((at0 ^ (ar0 & 7)) << 4);
  char* adst1 = AsB + ar1 * 128 + ((at1 ^ (ar1 & 7)) << 4);
  const bool aok0 = (row0 + ar0) < NITEM;
  const bool aok1 = (row0 + ar1) < NITEM;

  for (int k0 = 0; k0 < DFEAT; k0 += 64) {
    // ---- issue B stage: 4096 slots, 8 gload_lds per wave, lane covers slot ----
    #pragma unroll
    for (int j = 0; j < 8; ++j) {
      int q = (wid * 8 + j) * 64 + lane;     // linear LDS slot 0..4095
      int r = q >> 3, t = q & 7;
      const ushort* src = BT + (size_t)r * DFEAT + k0 + ((t ^ (r & 7)) << 3);
      __builtin_amdgcn_global_load_lds(
          (const __attribute__((address_space(1))) void*)src,
          (__attribute__((address_space(3))) void*)(BsB + (size_t)(wid * 8 + j) * 1024),
          16, 0, 0);
    }
    // ---- A stage: fp32 load -> bf16 cvt -> swizzled ds_write (2 slots/thr) ----
    {
      float4 v0 = make_float4(0.f,0.f,0.f,0.f), v1 = v0, v2 = v0, v3 = v0;
      if (aok0) {
        const float* s = A + asrc0 + k0;
        v0 = *(const float4*)s; v1 = *(const float4*)(s + 4);
      }
      if (aok1) {
        const float* s = A + asrc1 + k0;
        v2 = *(const float4*)s; v3 = *(const float4*)(s + 4);
      }
      uint4 p0, p1;
      p0.x = pk2bf(v0.x, v0.y); p0.y = pk2bf(v0.z, v0.w);
      p0.z = pk2bf(v1.x, v1.y); p0.w = pk2bf(v1.z, v1.w);
      p1.x = pk2bf(v2.x, v2.y); p1.y = pk2bf(v2.z, v2.w);
      p1.z = pk2bf(v3.x, v3.y); p1.w = pk2bf(v3.z, v3.w);
      *(uint4*)adst0 = p0;
      *(uint4*)adst1 = p1;
    }
    __syncthreads();   // drains gload_lds (vmcnt) + ds_writes (lgkm)

    // ---- compute: 2 k-halves x (4 a-frags, 8 b-frags, 32 MFMA) ----
    #pragma unroll
    for (int kk = 0; kk < 2; ++kk) {
      const int c8 = kk * 4 + kq;
      const int sx = (c8 ^ l7) << 4;
      bf16x8 a[4], b[8];
      #pragma unroll
      for (int m = 0; m < 4; ++m)
        a[m] = *(const bf16x8*)(AsB + (wr * 64 + m * 16 + lr) * 128 + sx);
      #pragma unroll
      for (int n = 0; n < 8; ++n)
        b[n] = *(const bf16x8*)(BsB + (wc * 128 + n * 16 + lr) * 128 + sx);
      #pragma unroll
      for (int m = 0; m < 4; ++m)
        #pragma unroll
        for (int n = 0; n < 8; ++n)
          acc[m][n] = __builtin_amdgcn_mfma_f32_16x16x32_bf16(a[m], b[n], acc[m][n], 0, 0, 0);
    }
    __syncthreads();   // before overwriting LDS next iteration
  }

  // ---- epilogue: +bias, leakyrelu, bf16 store ----
  #pragma unroll
  for (int n = 0; n < 8; ++n) {
    int col = wc * 128 + n * 16 + lr;
    float bv = bias[col];
    #pragma unroll
    for (int m = 0; m < 4; ++m) {
      #pragma unroll
      for (int i = 0; i < 4; ++i) {
        int row = row0 + wr * 64 + m * 16 + kq * 4 + i;
        float v = acc[m][n][i] + bv;
        v = v > 0.f ? v : 0.01f * v;
        Hid[(size_t)row * DHID + col] = f2bf(v);
      }
    }
  }
}

#define BM 128
#define BK 32
#define LDW 40   // padded LDS row stride (ushorts)

// ---------------- GEMM2: item_feat = hidden @ W2 + b2 -> X rows [NUSER..NTOT) fp32 ----------------
__global__ __launch_bounds__(256) void gemm2_kernel(
    const ushort* __restrict__ A,   // Hid [MPAD][DHID] bf16
    const ushort* __restrict__ BT,  // W2T [DLAT][DHID] bf16
    const float* __restrict__ bias, // [DLAT]
    float* __restrict__ X)          // [NTOT][DLAT]
{
  __shared__ ushort As[BM][LDW];
  __shared__ ushort Bs[BM][LDW];
  const int tid = threadIdx.x;
  const int lane = tid & 63;
  const int wid = tid >> 6;
  const int wr = wid >> 1, wc = wid & 1;
  const int row0 = blockIdx.x * BM;

  f32x4 acc[4][4];
  const f32x4 z = {0.f, 0.f, 0.f, 0.f};
  #pragma unroll
  for (int m = 0; m < 4; ++m)
    #pragma unroll
    for (int n = 0; n < 4; ++n) acc[m][n] = z;

  const int lrow = lane & 15;
  const int kb = (lane >> 4) * 8;

  for (int k0 = 0; k0 < DHID; k0 += BK) {
    #pragma unroll
    for (int j = 0; j < 2; ++j) {
      int idx = tid + j * 256;
      int r = idx >> 2;
      int c8 = (idx & 3) << 3;
      *(uint4*)&As[r][c8] = *(const uint4*)(A + (size_t)(row0 + r) * DHID + k0 + c8);
      *(uint4*)&Bs[r][c8] = *(const uint4*)(BT + (size_t)r * DHID + k0 + c8);
    }
    __syncthreads();
    bf16x8 a[4], b[4];
    #pragma unroll
    for (int m = 0; m < 4; ++m) a[m] = *(const bf16x8*)&As[wr * 64 + m * 16 + lrow][kb];
    #pragma unroll
    for (int n = 0; n < 4; ++n) b[n] = *(const bf16x8*)&Bs[wc * 64 + n * 16 + lrow][kb];
    #pragma unroll
    for (int m = 0; m < 4; ++m)
      #pragma unroll
      for (int n = 0; n < 4; ++n)
        acc[m][n] = __builtin_amdgcn_mfma_f32_16x16x32_bf16(a[m], b[n], acc[m][n], 0, 0, 0);
    __syncthreads();
  }
  #pragma unroll
  for (int n = 0; n < 4; ++n) {
    int col = wc * 64 + n * 16 + lrow;
    float bv = bias[col];
    #pragma unroll
    for (int m = 0; m < 4; ++m) {
      #pragma unroll
      for (int i = 0; i < 4; ++i) {
        int row = row0 + wr * 64 + m * 16 + (lane >> 4) * 4 + i;
        if (row < NITEM)
          X[(size_t)(NUSER + row) * DLAT + col] = acc[m][n][i] + bv;
      }
    }
  }
}

// ---------------- prep: transpose + fp32->bf16 for W1, W2 ----------------
__global__ void prep_w1t(const float* __restrict__ W1, ushort* __restrict__ W1T) {
  int idx = blockIdx.x * 256 + threadIdx.x;
  int n = idx >> 12, k = idx & 4095;
  W1T[idx] = f2bf(W1[(size_t)k * DHID + n]);
}
__global__ void prep_w2t(const float* __restrict__ W2, ushort* __restrict__ W2T) {
  int idx = blockIdx.x * 256 + threadIdx.x;
  int n = idx >> 9, k = idx & 511;
  W2T[idx] = f2bf(W2[(size_t)k * DLAT + n]);
}

// ---------------- normalize rows of x (users from preference, items in-place) ----------------
__global__ __launch_bounds__(256) void normalize_kernel(
    const float* __restrict__ pref, float* __restrict__ X) {
  int gw = (blockIdx.x * 256 + threadIdx.x) >> 6;
  int lane = threadIdx.x & 63;
  if (gw >= NTOT) return;
  const float* src = (gw < NUSER) ? (pref + (size_t)gw * DLAT) : (X + (size_t)gw * DLAT);
  float2 v = *(const float2*)(src + lane * 2);
  float s = v.x * v.x + v.y * v.y;
  #pragma unroll
  for (int off = 32; off; off >>= 1) s += __shfl_xor(s, off, 64);
  float inv = 1.0f / fmaxf(sqrtf(s), 1e-12f);
  float2 o; o.x = v.x * inv; o.y = v.y * inv;
  *(float2*)(X + (size_t)gw * DLAT + lane * 2) = o;
}

// ---------------- graph prep: CSR by destination ----------------
__global__ void count_kernel(const int* __restrict__ col, int* __restrict__ cnt, int E) {
  int e = blockIdx.x * 256 + threadIdx.x;
  if (e < E) atomicAdd(&cnt[col[e]], 1);
}
__global__ void dinv_kernel(const int* __restrict__ cnt, float* __restrict__ dinv, int n) {
  int i = blockIdx.x * 256 + threadIdx.x;
  if (i < n) dinv[i] = rsqrtf((float)cnt[i]);
}

// single-block chunked exclusive scan over n counts -> off[0..n]
__global__ __launch_bounds__(1024) void scan_kernel(const int* __restrict__ cnt,
                                                    int* __restrict__ off, int n) {
  __shared__ int ws[16];
  __shared__ int wexcl[16];
  __shared__ int total_s;
  __shared__ int carry_s;
  const int tid = threadIdx.x, lane = tid & 63, wv = tid >> 6;
  if (tid == 0) carry_s = 0;
  __syncthreads();
  for (int base = 0; base < n; base += 1024) {
    int i = base + tid;
    int v = (i < n) ? cnt[i] : 0;
    int x = v;
    #pragma unroll
    for (int o = 1; o < 64; o <<= 1) {
      int t = __shfl_up(x, o, 64);
      if (lane >= o) x += t;
    }
    if (lane == 63) ws[wv] = x;
    __syncthreads();
    if (tid < 16) {
      int y = ws[tid];
      #pragma unroll
      for (int o = 1; o < 16; o <<= 1) {
        int t = __shfl_up(y, o, 64);
        if (tid >= o) y += t;
      }
      wexcl[tid] = y - ws[tid];
      if (tid == 15) total_s = y;
    }
    __syncthreads();
    int carry = carry_s;
    if (i < n) off[i] = carry + wexcl[wv] + (x - v);
    __syncthreads();
    if (tid == 0) carry_s = carry + total_s;
    __syncthreads();
  }
  if (threadIdx.x == 0) off[n] = carry_s;
}

// fill CSR slots: (src, edge-norm) packed per dst segment
__global__ void fill_kernel(const int* __restrict__ row, const int* __restrict__ col,
                            const float* __restrict__ dinv, const int* __restrict__ off,
                            int* __restrict__ cur, int2* __restrict__ srcw, int E) {
  int e = blockIdx.x * 256 + threadIdx.x;
  if (e >= E) return;
  int r = row[e], c = col[e];
  float w = dinv[r] * dinv[c];
  int p = atomicAdd(&cur[c], 1);
  int2 pk; pk.x = r; pk.y = __float_as_int(w);
  srcw[off[c] + p] = pk;
}

// ---------------- SpMM: one wave per node, register accumulate, no atomics ----------------
template <int FINAL>
__global__ __launch_bounds__(256) void spmm_kernel(
    const int2* __restrict__ srcw, const int* __restrict__ off,
    const float* __restrict__ h, float* __restrict__ hout,
    const float* __restrict__ addA, const float* __restrict__ addB) {
  int node = (int)((blockIdx.x * 256 + threadIdx.x) >> 6);
  int lane = threadIdx.x & 63;
  if (node >= NTOT) return;
  int p = off[node], pend = off[node + 1];
  float ax = 0.f, ay = 0.f;
  for (; p + 1 < pend; p += 2) {
    int2 e0 = srcw[p];
    int2 e1 = srcw[p + 1];
    float w0 = __int_as_float(e0.y);
    float w1 = __int_as_float(e1.y);
    float2 v0 = *(const float2*)(h + (size_t)e0.x * DLAT + lane * 2);
    float2 v1 = *(const float2*)(h + (size_t)e1.x * DLAT + lane * 2);
    ax += w0 * v0.x + w1 * v1.x;
    ay += w0 * v0.y + w1 * v1.y;
  }
  if (p < pend) {
    int2 e0 = srcw[p];
    float w0 = __int_as_float(e0.y);
    float2 v0 = *(const float2*)(h + (size_t)e0.x * DLAT + lane * 2);
    ax += w0 * v0.x;
    ay += w0 * v0.y;
  }
  size_t o = (size_t)node * DLAT + lane * 2;
  if (FINAL) {
    float2 a = *(const float2*)(addA + o);
    float2 b = *(const float2*)(addB + o);
    ax += a.x + b.x;
    ay += a.y + b.y;
  }
  float2 r; r.x = ax; r.y = ay;
  *(float2*)(hout + o) = r;
}

extern "C" void kernel_launch(void* const* d_in, const int* in_sizes, int n_in,
                              void* d_out, int out_size, void* d_ws, size_t ws_size,
                              hipStream_t stream) {
  const float* features  = (const float*)d_in[0];
  const float* preference = (const float*)d_in[1];
  const float* W1 = (const float*)d_in[2];
  const float* b1 = (const float*)d_in[3];
  const float* W2 = (const float*)d_in[4];
  const float* b2 = (const float*)d_in[5];
  const int*   edges = (const int*)d_in[6];
  const int E = in_sizes[6] / 2;
  const int* erow = edges;
  const int* ecol = edges + E;
  float* out = (float*)d_out;

  char* ws = (char*)d_ws;
  size_t off_b = 0;
  auto alloc = [&](size_t bytes) {
    void* p = ws + off_b;
    off_b = (off_b + bytes + 255) & ~(size_t)255;
    return p;
  };
  ushort* W1T  = (ushort*)alloc((size_t)DHID * DFEAT * 2);   // 4.2 MB
  ushort* W2T  = (ushort*)alloc((size_t)DLAT * DHID * 2);    // 0.13 MB
  ushort* Hid  = (ushort*)alloc((size_t)MPAD * DHID * 2);    // 51.2 MB
  float*  X    = (float*)alloc((size_t)NTOT * DLAT * 4);     // 51.2 MB
  float*  hA   = (float*)alloc((size_t)NTOT * DLAT * 4);     // 51.2 MB
  int*    cnt  = (int*)alloc((size_t)NTOT * 4);
  int*    offs = (int*)alloc((size_t)(NTOT + 1) * 4);
  int*    cur  = (int*)alloc((size_t)NTOT * 4);
  float*  dinv = (float*)alloc((size_t)NTOT * 4);
  int2*   srcw = (int2*)alloc((size_t)E * 8);                // 12.8 MB

  // projection MLP + normalize
  prep_w1t<<<(DHID * DFEAT) / 256, 256, 0, stream>>>(W1, W1T);
  prep_w2t<<<(DLAT * DHID) / 256, 256, 0, stream>>>(W2, W2T);
  gemm1_kernel<<<MTILES, 512, 80 * 1024, stream>>>(features, W1T, b1, Hid);
  gemm2_kernel<<<MTILES, 256, 0, stream>>>(Hid, W2T, b2, X);
  normalize_kernel<<<(NTOT * 64 + 255) / 256, 256, 0, stream>>>(preference, X);

  // CSR build (by destination); symmetric edge list => cnt doubles as deg
  hipMemsetAsync(cnt, 0, (size_t)NTOT * 4, stream);
  count_kernel<<<(E + 255) / 256, 256, 0, stream>>>(ecol, cnt, E);
  dinv_kernel<<<(NTOT + 255) / 256, 256, 0, stream>>>(cnt, dinv, NTOT);
  scan_kernel<<<1, 1024, 0, stream>>>(cnt, offs, NTOT);
  hipMemsetAsync(cur, 0, (size_t)NTOT * 4, stream);
  fill_kernel<<<(E + 255) / 256, 256, 0, stream>>>(erow, ecol, dinv, offs, cur, srcw, E);

  // two propagation layers; layer 2 fuses out = X + h1 + h2
  spmm_kernel<0><<<(NTOT * 64 + 255) / 256, 256, 0, stream>>>(srcw, offs, X, hA, nullptr, nullptr);
  spmm_kernel<1><<<(NTOT * 64 + 255) / 256, 256, 0, stream>>>(srcw, offs, hA, out, X, hA);

  // output 1: preference passthrough
  hipMemcpyAsync(out + (size_t)NTOT * DLAT, preference, (size_t)NUSER * DLAT * 4,
                 hipMemcpyDeviceToDevice, stream);
}